// Round 17
// baseline (51.887 us; speedup 1.0000x reference)
//
#include <hip/hip_runtime.h>
#include <stdint.h>

#define NFEAT 16
#define NCOLS 969            // 1 bias + 16 deg1 + 136 deg2 + 816 deg3
#define NROWS 65536
#define PROWS 16             // rows per pass (double-buffered)
#define NPASS 16             // 256 rows per block / 16
#define NTHREADS 512
#define NPROD 192            // 3 producer waves
#define NCONS 320            // 5 consumer waves
#define PASS_F4 (PROWS * NCOLS / 4)   // 3876 float4 groups per pass

typedef float floatx4 __attribute__((ext_vector_type(4)));

// ---------------------------------------------------------------------------
// Static compute of cols [CB, CE) of one row into packed LDS row (stride 969).
// All 969 columns emitted in sklearn/jax reference order (verified absmax 0.0
// R1/R3-R16); out-of-range emits are compile-time dead. Scalar ds_write_b32:
// 16 rows x stride 969 (969%32=9, gcd(9,32)=1) -> 16 lanes hit 16 distinct
// banks: conflict-free.
// ---------------------------------------------------------------------------
template<int CB, int CE>
__device__ __forceinline__ void compute_range(const float* xr, float* ldsrow) {
    int col = 0;
#define EMIT(P) do { if (col >= CB && col < CE) ldsrow[col] = (P); ++col; } while (0)
    EMIT(1.0f);                                   // bias
    #pragma unroll
    for (int i = 0; i < NFEAT; ++i) EMIT(xr[i]);  // degree 1
    #pragma unroll
    for (int i = 0; i < NFEAT; ++i)               // degree 2
        #pragma unroll
        for (int j = i; j < NFEAT; ++j) EMIT(xr[i] * xr[j]);
    #pragma unroll
    for (int i = 0; i < NFEAT; ++i)               // degree 3 (x_i*x_j via CSE)
        #pragma unroll
        for (int j = i; j < NFEAT; ++j)
            #pragma unroll
            for (int k = j; k < NFEAT; ++k) EMIT((xr[i] * xr[j]) * xr[k]);
#undef EMIT
}

// 12 ranges of 81 cols (last: 891..969 = 78). Uniform per 16-lane group;
// each of the 3 producer waves runs 4 serial bodies.
__device__ __forceinline__ void compute_dispatch(int range, const float* xr, float* ldsrow) {
    switch (range) {
        case  0: compute_range<  0,  81>(xr, ldsrow); break;
        case  1: compute_range< 81, 162>(xr, ldsrow); break;
        case  2: compute_range<162, 243>(xr, ldsrow); break;
        case  3: compute_range<243, 324>(xr, ldsrow); break;
        case  4: compute_range<324, 405>(xr, ldsrow); break;
        case  5: compute_range<405, 486>(xr, ldsrow); break;
        case  6: compute_range<486, 567>(xr, ldsrow); break;
        case  7: compute_range<567, 648>(xr, ldsrow); break;
        case  8: compute_range<648, 729>(xr, ldsrow); break;
        case  9: compute_range<729, 810>(xr, ldsrow); break;
        case 10: compute_range<810, 891>(xr, ldsrow); break;
        case 11: compute_range<891, 969>(xr, ldsrow); break;
    }
}

// Raw barrier WITHOUT vmcnt drain: LDS visibility needs only lgkmcnt(0);
// in-flight global stores keep draining across it.
__device__ __forceinline__ void lds_barrier() {
    asm volatile("s_waitcnt lgkmcnt(0)" ::: "memory");
    __builtin_amdgcn_s_barrier();
}

// ---------------------------------------------------------------------------
// Producer/consumer, 3+5 waves (R16 rebalance):
//   waves 0-2 (tid 0..191):   compute 16-row passes into buf[p&1]
//   waves 3-7 (tid 192..511): batched flat copy buf[p&1] -> out
// Consumer: single depth-12 read batch (48 VGPR) + 36-lane tail, then 12
// stores back-to-back: ~12 KB in flight per wave x 5 waves = 60 KB/CU.
// Pacing is vmcnt register-reuse at the next pass's reads = HBM drain rate;
// producers (~1.5-2k cyc/pass) always beat the ~5.4k cyc drain to the barrier.
// Barrier pairing (16 each side, race-free as in R12/R16): producer writes
// buf[(p+1)&1] while consumer reads buf[p&1] -> disjoint.
// NOTE: block of 512 -> 2 waves/SIMD -> 256-VGPR cap; 81-col bodies fit
// (60-col fit with margin in R13; EMIT writes products immediately).
// ---------------------------------------------------------------------------
__global__ void __launch_bounds__(NTHREADS, 1)
poly_pc(const float* __restrict__ x, float* __restrict__ out) {
    __shared__ __align__(16) float buf[2][PROWS * NCOLS];   // 2 x 62,016 B

    const int tid  = threadIdx.x;
    const int base = blockIdx.x * (NPASS * PROWS);          // 256 rows per block

    if (tid < NPROD) {
        // ---------------- producers (waves 0-2) ----------------
        const int prow  = tid & 15;          // row within pass
        const int range = tid >> 4;          // 0..11
        const floatx4* xv = (const floatx4*)(x + (size_t)(base + prow) * NFEAT);
        floatx4 c0 = xv[0], c1 = xv[1], c2 = xv[2], c3 = xv[3];

        for (int p = 0; p < NPASS; ++p) {
            float xr[NFEAT] = {c0[0],c0[1],c0[2],c0[3], c1[0],c1[1],c1[2],c1[3],
                               c2[0],c2[1],c2[2],c2[3], c3[0],c3[1],c3[2],c3[3]};
            // prefetch next pass's x-row; has a full pass (~5.4k cyc) to land
            if (p + 1 < NPASS) {
                const floatx4* nv = (const floatx4*)
                    (x + (size_t)(base + (p + 1) * PROWS + prow) * NFEAT);
                c0 = nv[0]; c1 = nv[1]; c2 = nv[2]; c3 = nv[3];
            }
            compute_dispatch(range, xr, &buf[p & 1][prow * NCOLS]);
            lds_barrier();                                   // barrier p
        }
    } else {
        // ---------------- consumers (waves 3-7) ----------------
        const int ctid = tid - NPROD;        // 0..319
        const bool has_tail = ctid < (PASS_F4 - 12 * NCONS);   // 36 lanes
        for (int p = 0; p < NPASS; ++p) {
            lds_barrier();                                   // barrier p
            const floatx4* src4 = (const floatx4*)buf[p & 1];
            floatx4* dst4 = (floatx4*)(out + (size_t)(base + p * PROWS) * NCOLS);

            // depth-12 read batch + tail, then all stores back-to-back
            floatx4 r[12];
            #pragma unroll
            for (int s = 0; s < 12; ++s) r[s] = src4[ctid + s * NCONS];
            floatx4 t;
            if (has_tail) t = src4[ctid + 12 * NCONS];
            #pragma unroll
            for (int s = 0; s < 12; ++s) dst4[ctid + s * NCONS] = r[s];
            if (has_tail) dst4[ctid + 12 * NCONS] = t;
        }
    }
}

extern "C" void kernel_launch(void* const* d_in, const int* in_sizes, int n_in,
                              void* d_out, int out_size, void* d_ws, size_t ws_size,
                              hipStream_t stream) {
    const float* x = (const float*)d_in[0];
    float* out = (float*)d_out;
    // 256 persistent blocks (1 per CU), 16 double-buffered 16-row passes,
    // 3 producer + 5 consumer waves.
    poly_pc<<<256, NTHREADS, 0, stream>>>(x, out);
}

// Round 18
// 50.376 us; speedup vs baseline: 1.0300x; 1.0300x over previous
//
#include <hip/hip_runtime.h>
#include <stdint.h>

#define NFEAT 16
#define NCOLS 969            // 1 bias + 16 deg1 + 136 deg2 + 816 deg3
#define NROWS 65536
#define PROWS 16             // rows per pass (double-buffered)
#define NPASS 16             // 256 rows per block / 16
#define NTHREADS 512
#define PASS_F4 (PROWS * NCOLS / 4)   // 3876 float4 groups per pass

typedef float floatx4 __attribute__((ext_vector_type(4)));

// ---------------------------------------------------------------------------
// Static compute of cols [CB, CE) of one row into packed LDS row (stride 969).
// All 969 columns emitted in sklearn/jax reference order (verified absmax 0.0
// R1/R3-R17); out-of-range emits are compile-time dead. Scalar ds_write_b32:
// 16 rows x stride 969 (969%32=9, gcd(9,32)=1) -> 16 lanes hit 16 distinct
// banks: conflict-free.
// ---------------------------------------------------------------------------
template<int CB, int CE>
__device__ __forceinline__ void compute_range(const float* xr, float* ldsrow) {
    int col = 0;
#define EMIT(P) do { if (col >= CB && col < CE) ldsrow[col] = (P); ++col; } while (0)
    EMIT(1.0f);                                   // bias
    #pragma unroll
    for (int i = 0; i < NFEAT; ++i) EMIT(xr[i]);  // degree 1
    #pragma unroll
    for (int i = 0; i < NFEAT; ++i)               // degree 2
        #pragma unroll
        for (int j = i; j < NFEAT; ++j) EMIT(xr[i] * xr[j]);
    #pragma unroll
    for (int i = 0; i < NFEAT; ++i)               // degree 3 (x_i*x_j via CSE)
        #pragma unroll
        for (int j = i; j < NFEAT; ++j)
            #pragma unroll
            for (int k = j; k < NFEAT; ++k) EMIT((xr[i] * xr[j]) * xr[k]);
#undef EMIT
}

// 16 ranges of ~60 cols (R16's proven split: small live sets, no spill).
__device__ __forceinline__ void compute_dispatch(int range, const float* xr, float* ldsrow) {
    switch (range) {   // uniform per 16-lane group; 4 serial bodies per wave
        case  0: compute_range<  0,  60>(xr, ldsrow); break;
        case  1: compute_range< 60, 120>(xr, ldsrow); break;
        case  2: compute_range<120, 180>(xr, ldsrow); break;
        case  3: compute_range<180, 240>(xr, ldsrow); break;
        case  4: compute_range<240, 300>(xr, ldsrow); break;
        case  5: compute_range<300, 360>(xr, ldsrow); break;
        case  6: compute_range<360, 420>(xr, ldsrow); break;
        case  7: compute_range<420, 480>(xr, ldsrow); break;
        case  8: compute_range<480, 540>(xr, ldsrow); break;
        case  9: compute_range<540, 600>(xr, ldsrow); break;
        case 10: compute_range<600, 660>(xr, ldsrow); break;
        case 11: compute_range<660, 720>(xr, ldsrow); break;
        case 12: compute_range<720, 780>(xr, ldsrow); break;
        case 13: compute_range<780, 840>(xr, ldsrow); break;
        case 14: compute_range<840, 900>(xr, ldsrow); break;
        case 15: compute_range<900, 969>(xr, ldsrow); break;
    }
}

// Raw barrier WITHOUT vmcnt drain: LDS visibility needs only lgkmcnt(0);
// in-flight global stores keep draining across it.
__device__ __forceinline__ void lds_barrier() {
    asm volatile("s_waitcnt lgkmcnt(0)" ::: "memory");
    __builtin_amdgcn_s_barrier();
}

// ---------------------------------------------------------------------------
// Producer/consumer, 4+4 waves (R16 base, 44.2us) with ONE change: consumer
// issues a SINGLE depth-15 read batch then 15 stores back-to-back (+36-lane
// tail), instead of 8+7 sub-batches. Peak outstanding stores/wave ~15
// (~15.4 KB) x 4 waves ~= 61 KB/CU in flight (vs ~32 KB) -- 2x Little's-law
// margin against ~900cyc HBM store latency; drain stays saturated across
// barrier boundaries.
//   waves 0-3 (tid 0..255):   compute 16-row passes into buf[p&1]
//   waves 4-7 (tid 256..511): batched flat copy buf[p&1] -> out
// Barrier pairing (16 each side, race-free as in R12/R16): producer writes
// buf[(p+1)&1] while consumer reads buf[p&1] -> disjoint.
// ---------------------------------------------------------------------------
__global__ void __launch_bounds__(NTHREADS, 1)
poly_pc(const float* __restrict__ x, float* __restrict__ out) {
    __shared__ __align__(16) float buf[2][PROWS * NCOLS];   // 2 x 62,016 B

    const int tid  = threadIdx.x;
    const int base = blockIdx.x * (NPASS * PROWS);          // 256 rows per block

    if (tid < 256) {
        // ---------------- producers (waves 0-3) ----------------
        const int prow  = tid & 15;          // row within pass
        const int range = tid >> 4;          // 0..15
        const floatx4* xv = (const floatx4*)(x + (size_t)(base + prow) * NFEAT);
        floatx4 c0 = xv[0], c1 = xv[1], c2 = xv[2], c3 = xv[3];

        for (int p = 0; p < NPASS; ++p) {
            float xr[NFEAT] = {c0[0],c0[1],c0[2],c0[3], c1[0],c1[1],c1[2],c1[3],
                               c2[0],c2[1],c2[2],c2[3], c3[0],c3[1],c3[2],c3[3]};
            // prefetch next pass's x-row; has a full pass (~5.4k cyc) to land
            if (p + 1 < NPASS) {
                const floatx4* nv = (const floatx4*)
                    (x + (size_t)(base + (p + 1) * PROWS + prow) * NFEAT);
                c0 = nv[0]; c1 = nv[1]; c2 = nv[2]; c3 = nv[3];
            }
            compute_dispatch(range, xr, &buf[p & 1][prow * NCOLS]);
            lds_barrier();                                   // barrier p
        }
    } else {
        // ---------------- consumers (waves 4-7) ----------------
        const int ctid = tid - 256;          // 0..255
        const bool has_tail = ctid < (PASS_F4 - 15 * 256);   // 36 lanes
        for (int p = 0; p < NPASS; ++p) {
            lds_barrier();                                   // barrier p
            const floatx4* src4 = (const floatx4*)buf[p & 1];
            floatx4* dst4 = (floatx4*)(out + (size_t)(base + p * PROWS) * NCOLS);

            // single depth-15 read batch (+tail), then all stores back-to-back
            floatx4 r[15];
            #pragma unroll
            for (int s = 0; s < 15; ++s) r[s] = src4[ctid + s * 256];
            floatx4 t;
            if (has_tail) t = src4[ctid + 15 * 256];
            #pragma unroll
            for (int s = 0; s < 15; ++s) dst4[ctid + s * 256] = r[s];
            if (has_tail) dst4[ctid + 15 * 256] = t;
        }
    }
}

extern "C" void kernel_launch(void* const* d_in, const int* in_sizes, int n_in,
                              void* d_out, int out_size, void* d_ws, size_t ws_size,
                              hipStream_t stream) {
    const float* x = (const float*)d_in[0];
    float* out = (float*)d_out;
    // 256 persistent blocks (1 per CU), 16 double-buffered 16-row passes,
    // 4 producer + 4 consumer waves.
    poly_pc<<<256, NTHREADS, 0, stream>>>(x, out);
}

// Round 19
// 44.389 us; speedup vs baseline: 1.1689x; 1.1349x over previous
//
#include <hip/hip_runtime.h>
#include <stdint.h>

#define NFEAT 16
#define NCOLS 969            // 1 bias + 16 deg1 + 136 deg2 + 816 deg3
#define NROWS 65536
#define PROWS 16             // rows per pass (double-buffered)
#define NPASS 16             // 256 rows per block / 16
#define NTHREADS 512
#define PASS_F4 (PROWS * NCOLS / 4)   // 3876 float4 groups per pass

typedef float floatx4 __attribute__((ext_vector_type(4)));

// ---------------------------------------------------------------------------
// Static compute of cols [CB, CE) of one row into packed LDS row (stride 969).
// All 969 columns emitted in sklearn/jax reference order (verified absmax 0.0
// R1/R3-R18); out-of-range emits are compile-time dead. Scalar ds_write_b32:
// 16 rows x stride 969 (969%32=9, gcd(9,32)=1) -> 16 lanes hit 16 distinct
// banks: conflict-free.
// ---------------------------------------------------------------------------
template<int CB, int CE>
__device__ __forceinline__ void compute_range(const float* xr, float* ldsrow) {
    int col = 0;
#define EMIT(P) do { if (col >= CB && col < CE) ldsrow[col] = (P); ++col; } while (0)
    EMIT(1.0f);                                   // bias
    #pragma unroll
    for (int i = 0; i < NFEAT; ++i) EMIT(xr[i]);  // degree 1
    #pragma unroll
    for (int i = 0; i < NFEAT; ++i)               // degree 2
        #pragma unroll
        for (int j = i; j < NFEAT; ++j) EMIT(xr[i] * xr[j]);
    #pragma unroll
    for (int i = 0; i < NFEAT; ++i)               // degree 3 (x_i*x_j via CSE)
        #pragma unroll
        for (int j = i; j < NFEAT; ++j)
            #pragma unroll
            for (int k = j; k < NFEAT; ++k) EMIT((xr[i] * xr[j]) * xr[k]);
#undef EMIT
}

__device__ __forceinline__ void compute_dispatch(int range, const float* xr, float* ldsrow) {
    switch (range) {   // uniform per 16-lane group; 4 serial bodies per wave
        case  0: compute_range<  0,  60>(xr, ldsrow); break;
        case  1: compute_range< 60, 120>(xr, ldsrow); break;
        case  2: compute_range<120, 180>(xr, ldsrow); break;
        case  3: compute_range<180, 240>(xr, ldsrow); break;
        case  4: compute_range<240, 300>(xr, ldsrow); break;
        case  5: compute_range<300, 360>(xr, ldsrow); break;
        case  6: compute_range<360, 420>(xr, ldsrow); break;
        case  7: compute_range<420, 480>(xr, ldsrow); break;
        case  8: compute_range<480, 540>(xr, ldsrow); break;
        case  9: compute_range<540, 600>(xr, ldsrow); break;
        case 10: compute_range<600, 660>(xr, ldsrow); break;
        case 11: compute_range<660, 720>(xr, ldsrow); break;
        case 12: compute_range<720, 780>(xr, ldsrow); break;
        case 13: compute_range<780, 840>(xr, ldsrow); break;
        case 14: compute_range<840, 900>(xr, ldsrow); break;
        case 15: compute_range<900, 969>(xr, ldsrow); break;
    }
}

// Raw barrier WITHOUT vmcnt drain: LDS visibility needs only lgkmcnt(0);
// in-flight global stores keep draining across it.
__device__ __forceinline__ void lds_barrier() {
    asm volatile("s_waitcnt lgkmcnt(0)" ::: "memory");
    __builtin_amdgcn_s_barrier();
}

// ---------------------------------------------------------------------------
// Producer/consumer, 4+4 waves (R16 configuration -- measured optimum 44.2us):
//   waves 0-3 (tid 0..255):   compute 16-row passes into buf[p&1]
//   waves 4-7 (tid 256..511): batched flat copy buf[p&1] -> out
// Consumer batches 8 ds_read_b128 then 8 global_store_dwordx4 back-to-back,
// then a 7+tail batch: ~8-15 KB in flight per wave, 4 waves -> 32-60 KB/CU.
// (Measured: 2 consumer waves starve HBM at 6.2 B/cyc (R12); 5 consumer waves
// with 3 producers regress (R17); depth-15 monolithic batch regresses (R18).)
// Store waves pace on vmcnt register-reuse harmlessly; producers never wait
// on vmem. Barrier pairing (16 each side, race-free): producer writes
// buf[(p+1)&1] while consumer reads buf[p&1] -> disjoint.
// NOTE: no VGPR cap -- __launch_bounds__(512,1) (R7/R8/R9 spill lesson).
// ---------------------------------------------------------------------------
__global__ void __launch_bounds__(NTHREADS, 1)
poly_pc(const float* __restrict__ x, float* __restrict__ out) {
    __shared__ __align__(16) float buf[2][PROWS * NCOLS];   // 2 x 62,016 B

    const int tid  = threadIdx.x;
    const int base = blockIdx.x * (NPASS * PROWS);          // 256 rows per block

    if (tid < 256) {
        // ---------------- producers (waves 0-3) ----------------
        const int prow  = tid & 15;          // row within pass
        const int range = tid >> 4;          // 0..15
        const floatx4* xv = (const floatx4*)(x + (size_t)(base + prow) * NFEAT);
        floatx4 c0 = xv[0], c1 = xv[1], c2 = xv[2], c3 = xv[3];

        for (int p = 0; p < NPASS; ++p) {
            float xr[NFEAT] = {c0[0],c0[1],c0[2],c0[3], c1[0],c1[1],c1[2],c1[3],
                               c2[0],c2[1],c2[2],c2[3], c3[0],c3[1],c3[2],c3[3]};
            // prefetch next pass's x-row; has a full pass (~5.4k cyc) to land
            if (p + 1 < NPASS) {
                const floatx4* nv = (const floatx4*)
                    (x + (size_t)(base + (p + 1) * PROWS + prow) * NFEAT);
                c0 = nv[0]; c1 = nv[1]; c2 = nv[2]; c3 = nv[3];
            }
            compute_dispatch(range, xr, &buf[p & 1][prow * NCOLS]);
            lds_barrier();                                   // barrier p
        }
    } else {
        // ---------------- consumers (waves 4-7) ----------------
        const int ctid = tid - 256;          // 0..255
        for (int p = 0; p < NPASS; ++p) {
            lds_barrier();                                   // barrier p
            const floatx4* src4 = (const floatx4*)buf[p & 1];
            floatx4* dst4 = (floatx4*)(out + (size_t)(base + p * PROWS) * NCOLS);

            // batch 1: groups ctid + {0..7}*256  (all < 3876)
            floatx4 r[8];
            #pragma unroll
            for (int s = 0; s < 8; ++s) r[s] = src4[ctid + s * 256];
            #pragma unroll
            for (int s = 0; s < 8; ++s) dst4[ctid + s * 256] = r[s];

            // batch 2: groups ctid + {8..14}*256 (max 3839 < 3876) + tail s=15
            floatx4 q[7];
            #pragma unroll
            for (int s = 0; s < 7; ++s) q[s] = src4[ctid + (s + 8) * 256];
            floatx4 t;
            if (ctid < PASS_F4 - 3840) t = src4[ctid + 3840];   // 36 lanes
            #pragma unroll
            for (int s = 0; s < 7; ++s) dst4[ctid + (s + 8) * 256] = q[s];
            if (ctid < PASS_F4 - 3840) dst4[ctid + 3840] = t;
        }
    }
}

extern "C" void kernel_launch(void* const* d_in, const int* in_sizes, int n_in,
                              void* d_out, int out_size, void* d_ws, size_t ws_size,
                              hipStream_t stream) {
    const float* x = (const float*)d_in[0];
    float* out = (float*)d_out;
    // 256 persistent blocks (1 per CU), 16 double-buffered 16-row passes,
    // 4 producer + 4 consumer waves.
    poly_pc<<<256, NTHREADS, 0, stream>>>(x, out);
}